// Round 4
// baseline (162.849 us; speedup 1.0000x reference)
//
#include <hip/hip_runtime.h>
#include <stdint.h>

#define NH   16
#define EMB  1024
#define HD   64
#define BSZ  2
#define SEQ  2048
#define NROW (BSZ * SEQ)          // 4096

typedef __attribute__((ext_vector_type(8))) short bf16x8;   // 8 bf16 = 4 VGPRs
typedef __attribute__((ext_vector_type(4))) float f32x4;    // MFMA C/D

__device__ __forceinline__ uint16_t f2bf(float f) {
    union { float f; uint32_t i; } v; v.f = f;
    uint32_t r = v.i + 0x7FFFu + ((v.i >> 16) & 1u);  // RNE
    return (uint16_t)(r >> 16);
}
__device__ __forceinline__ uint32_t pack2(float a, float b) {
    return (uint32_t)f2bf(a) | ((uint32_t)f2bf(b) << 16);
}
// single-instruction packed f32->bf16 (lo=a, hi=b)
__device__ __forceinline__ uint32_t cvtpk(float a, float b) {
    uint32_t r;
    asm("v_cvt_pk_bf16_f32 %0, %1, %2" : "=v"(r) : "v"(a), "v"(b));
    return r;
}

// async global->LDS, 16 B per lane, wave-uniform LDS base
__device__ __forceinline__ void gl2lds16(const uint16_t* g, uint16_t* l) {
    __builtin_amdgcn_global_load_lds(
        static_cast<const uint32_t*>(static_cast<const void*>(g)),
        static_cast<uint32_t*>(static_cast<void*>(l)), 16, 0, 0);
}

// =====================================================================
// Prep (fused): blocks 0..2047 convert X fp32->bf16;
// blocks 2048..2335 transpose W fp32 [k][n] -> bf16 Wt[n][k].
// =====================================================================
__global__ __launch_bounds__(256) void prep(
    const float* __restrict__ X, uint16_t* __restrict__ Xbf,
    const float* __restrict__ Wq, const float* __restrict__ Wk,
    const float* __restrict__ Wv, uint16_t* __restrict__ Wqt,
    uint16_t* __restrict__ Wkt, uint16_t* __restrict__ Wvt)
{
    __shared__ uint16_t T[64][72];
    const int tid = threadIdx.x;
    if (blockIdx.x < 2048) {
        size_t idx = ((size_t)blockIdx.x * 256 + tid) * 8;
        float4 a = *(const float4*)&X[idx];
        float4 b = *(const float4*)&X[idx + 4];
        *(uint4*)&Xbf[idx] = make_uint4(pack2(a.x, a.y), pack2(a.z, a.w),
                                        pack2(b.x, b.y), pack2(b.z, b.w));
        return;
    }
    const int id = blockIdx.x - 2048;
    const float* W; uint16_t* Wt; int k0, n0, ldw;
    if (id < 256)      { W = Wq; Wt = Wqt; k0 = (id >> 4) * 64; n0 = (id & 15) * 64; ldw = EMB; }
    else if (id < 272) { W = Wk; Wt = Wkt; k0 = (id - 256) * 64; n0 = 0; ldw = HD; }
    else               { W = Wv; Wt = Wvt; k0 = (id - 272) * 64; n0 = 0; ldw = HD; }

    const int r = tid >> 2, c4 = (tid & 3) * 16;
#pragma unroll
    for (int i = 0; i < 4; ++i) {
        float4 wv = *(const float4*)&W[(size_t)(k0 + r) * ldw + n0 + c4 + 4 * i];
        T[r][c4 + 4 * i + 0] = f2bf(wv.x); T[r][c4 + 4 * i + 1] = f2bf(wv.y);
        T[r][c4 + 4 * i + 2] = f2bf(wv.z); T[r][c4 + 4 * i + 3] = f2bf(wv.w);
    }
    __syncthreads();
    const int n = tid >> 2, kk = (tid & 3) * 16;
    uint32_t o[8];
#pragma unroll
    for (int i = 0; i < 8; ++i)
        o[i] = (uint32_t)T[kk + 2 * i][n] | ((uint32_t)T[kk + 2 * i + 1][n] << 16);
    uint16_t* dst = &Wt[(size_t)(n0 + n) * EMB + k0 + kk];
    *(uint4*)dst       = make_uint4(o[0], o[1], o[2], o[3]);
    *(uint4*)(dst + 8) = make_uint4(o[4], o[5], o[6], o[7]);
}

// =====================================================================
// Kernel 1: MFMA projection GEMM v5.  64M x 128N tiles, BK=64,
// grid (9, 64) = 576 blocks.  (unchanged this round)
// =====================================================================
__global__ __launch_bounds__(256) void qkv_gemm_mfma5(
    const uint16_t* __restrict__ Xbf, const uint16_t* __restrict__ Wqt,
    const uint16_t* __restrict__ Wkt, const uint16_t* __restrict__ Wvt,
    float* __restrict__ Qout, uint16_t* __restrict__ Kbf,
    uint16_t* __restrict__ Vtbf)
{
    const int tid  = threadIdx.x;
    const int w    = tid >> 6, lane = tid & 63;
    const int l    = lane & 15, quad = lane >> 4;
    const int wm   = w & 1, wn = w >> 1;      // wave: 32m x 64n quadrant
    const int nt   = blockIdx.x;
    const int m0   = blockIdx.y * 64;

    __shared__ uint16_t As[2][64 * 64];    // 8 KB per buffer
    __shared__ uint16_t Bs[2][128 * 64];   // 16 KB per buffer

    // ---- staging: per-lane global source for swizzled LDS granules ----
    const uint16_t* gA[2]; uint32_t ldsA[2];
    const uint16_t* gB[4]; uint32_t ldsB[4];
#pragma unroll
    for (int i = 0; i < 2; ++i) {
        int G = (w * 2 + i) * 64 + lane;
        int r = G >> 3, cg = (G & 7) ^ (r & 7);
        gA[i] = &Xbf[(size_t)(m0 + r) * EMB + cg * 8];
        ldsA[i] = (w * 2 + i) * 512;              // elems, wave-uniform
    }
#pragma unroll
    for (int i = 0; i < 4; ++i) {
        int G = (w * 4 + i) * 64 + lane;
        int r = G >> 3, cg = (G & 7) ^ (r & 7);
        const uint16_t* bs;
        if (nt < 8)      bs = &Wqt[(size_t)(nt * 128 + r) * EMB + cg * 8];
        else if (r < 64) bs = &Wkt[(size_t)r * EMB + cg * 8];
        else             bs = &Wvt[(size_t)(r - 64) * EMB + cg * 8];
        gB[i] = bs;
        ldsB[i] = (w * 4 + i) * 512;
    }

    // ---- fragment read offsets (elems), loop-invariant ----
    uint32_t offA[2][2], offB[4][2];
#pragma unroll
    for (int i = 0; i < 2; ++i)
#pragma unroll
        for (int kh = 0; kh < 2; ++kh) {
            int row = 32 * wm + 16 * i + l;
            offA[i][kh] = row * 64 + (((kh * 4 + quad) ^ (row & 7)) * 8);
        }
#pragma unroll
    for (int j = 0; j < 4; ++j)
#pragma unroll
        for (int kh = 0; kh < 2; ++kh) {
            int row = 64 * wn + 16 * j + l;
            offB[j][kh] = row * 64 + (((kh * 4 + quad) ^ (row & 7)) * 8);
        }

    f32x4 acc[2][4] = {};

#pragma unroll
    for (int i = 0; i < 2; ++i) { gl2lds16(gA[i], &As[0][ldsA[i]]); gA[i] += 64; }
#pragma unroll
    for (int i = 0; i < 4; ++i) { gl2lds16(gB[i], &Bs[0][ldsB[i]]); gB[i] += 64; }
    __syncthreads();

    for (int ks = 0; ks < 16; ++ks) {
        const int cur = ks & 1, nxt = cur ^ 1;
        if (ks < 15) {
#pragma unroll
            for (int i = 0; i < 2; ++i) { gl2lds16(gA[i], &As[nxt][ldsA[i]]); gA[i] += 64; }
#pragma unroll
            for (int i = 0; i < 4; ++i) { gl2lds16(gB[i], &Bs[nxt][ldsB[i]]); gB[i] += 64; }
        }
#pragma unroll
        for (int kh = 0; kh < 2; ++kh) {
            bf16x8 af[2], bfr[4];
#pragma unroll
            for (int i = 0; i < 2; ++i) af[i] = *(const bf16x8*)&As[cur][offA[i][kh]];
#pragma unroll
            for (int j = 0; j < 4; ++j) bfr[j] = *(const bf16x8*)&Bs[cur][offB[j][kh]];
#pragma unroll
            for (int i = 0; i < 2; ++i)
#pragma unroll
                for (int j = 0; j < 4; ++j)
                    acc[i][j] = __builtin_amdgcn_mfma_f32_16x16x32_bf16(
                        af[i], bfr[j], acc[i][j], 0, 0, 0);
        }
        __syncthreads();
    }

    // ---- epilogue.  C layout: col = l (n), row = quad*4 + r (m). ----
    if (nt < 8) {             // Q -> fp32 d_out
#pragma unroll
        for (int i = 0; i < 2; ++i)
#pragma unroll
            for (int j = 0; j < 4; ++j)
#pragma unroll
                for (int r = 0; r < 4; ++r)
                    Qout[(size_t)(m0 + 32 * wm + 16 * i + 4 * quad + r) * EMB
                         + nt * 128 + 64 * wn + 16 * j + l] = acc[i][j][r];
    } else if (wn == 0) {     // K -> bf16 [t][d]
#pragma unroll
        for (int i = 0; i < 2; ++i)
#pragma unroll
            for (int j = 0; j < 4; ++j)
#pragma unroll
                for (int r = 0; r < 4; ++r)
                    Kbf[(size_t)(m0 + 32 * wm + 16 * i + 4 * quad + r) * HD
                        + 16 * j + l] = f2bf(acc[i][j][r]);
    } else {                  // V -> bf16 transposed [d][t]
#pragma unroll
        for (int i = 0; i < 2; ++i)
#pragma unroll
            for (int j = 0; j < 4; ++j)
#pragma unroll
                for (int r = 0; r < 4; ++r)
                    Vtbf[(size_t)(16 * j + l) * NROW
                         + m0 + 32 * wm + 16 * i + 4 * quad + r] = f2bf(acc[i][j][r]);
    }
}

// =====================================================================
// Kernel 2: causal MQA flash attention, COMPLEMENTARY-PAIR blocks.
// R15 (LDS-bandwidth attack; kernel was ~85% LDS-pipe-bound):
//  (a) pi-permuted K staging rows: LDS row m holds global K row
//      pi(m)=32*b5 + 8*(b3b2) + 4*b4 + b1b0  -> after QK, each lane's
//      16 exp2 outputs ARE the PV A-fragments in-order: 8 cvt_pk,
//      ZERO LDS round-trip for P.
//  (b) V fragments loaded global->VGPR (L2-hot, VMEM pipe idle):
//      no V staging, no V LDS reads.
//  In-loop LDS per wave: 8 b128 K reads + 2 b128 K stage writes (was
//  ~36 ops).  No setprio (R2 showed it hurts here).
// Grid (16, NH, BSZ) = 512 blocks (grid-limited: 2 blocks/CU).
// =====================================================================
__global__ __launch_bounds__(256) void mqa_attn(
    const uint16_t* __restrict__ Kbf, const uint16_t* __restrict__ Vtbf,
    float* __restrict__ Out)
{
    const int tid  = threadIdx.x;
    const int w    = tid >> 6;
    const int lane = tid & 63;
    const int l    = lane & 15;
    const int quad = lane >> 4;
    const int i  = blockIdx.x;            // 0..15 (i=0 longest)
    const int h  = blockIdx.y, b = blockIdx.z;
    const int qt0 = 31 - i, qt1 = i;      // big, small q-tile
    const int q00 = qt0 * 64, q01 = qt1 * 64;

    __shared__ __align__(16) uint16_t Ks[2][64][72];   // K tiles (dbuf), pi-rows
    __shared__ __align__(16) uint16_t Ps[2][64][72];   // Q staging only

    const float C = 0.125f * 1.4426950408889634f;      // scale * log2e
    const int sr = tid >> 2, sc = (tid & 3) * 16;
    // LDS row sr holds global k-row pi(sr)
    const int prow = (sr & 32) + ((sr >> 2) & 3) * 8 + ((sr & 16) >> 2) + (sr & 3);

    // ---- stage Q for both q-tiles (pre-scaled) into Ps (wave-local rows) ----
#pragma unroll
    for (int t = 0; t < 2; ++t) {
        const int q0t = t ? q01 : q00;
        const float* src = &Out[(size_t)(b * SEQ + q0t + sr) * EMB + h * HD + sc];
        float4 f0 = *(const float4*)(src + 0);
        float4 f1 = *(const float4*)(src + 4);
        float4 f2 = *(const float4*)(src + 8);
        float4 f3 = *(const float4*)(src + 12);
        *(uint4*)&Ps[t][sr][sc] =
            make_uint4(pack2(f0.x * C, f0.y * C), pack2(f0.z * C, f0.w * C),
                       pack2(f1.x * C, f1.y * C), pack2(f1.z * C, f1.w * C));
        *(uint4*)&Ps[t][sr][sc + 8] =
            make_uint4(pack2(f2.x * C, f2.y * C), pack2(f2.z * C, f2.w * C),
                       pack2(f3.x * C, f3.y * C), pack2(f3.z * C, f3.w * C));
    }

    // ---- K tile 0 -> LDS (pi rows); K tile 1 -> regs ----
    uint4 kg0, kg1;
    {
        const uint4* ks = (const uint4*)&Kbf[(size_t)(b * SEQ + prow) * HD + sc];
        kg0 = ks[0]; kg1 = ks[1];
    }
    *(uint4*)&Ks[0][sr][sc]     = kg0;
    *(uint4*)&Ks[0][sr][sc + 8] = kg1;
    {   // qt0 >= 16 always, tile 1 exists
        const uint4* ks = (const uint4*)&Kbf[(size_t)(b * SEQ + 64 + prow) * HD + sc];
        kg0 = ks[0]; kg1 = ks[1];
    }
    __syncthreads();

    // ---- Q B-fragments for both q-tiles ----
    bf16x8 qf[2][2];
#pragma unroll
    for (int t = 0; t < 2; ++t) {
        qf[t][0] = *(const bf16x8*)&Ps[t][16 * w + l][quad * 8];
        qf[t][1] = *(const bf16x8*)&Ps[t][16 * w + l][32 + quad * 8];
    }

    bf16x8 ones;
#pragma unroll
    for (int j = 0; j < 8; ++j) ones[j] = (short)0x3F80;   // bf16 1.0

    f32x4 accO[2][4] = {};
    f32x4 accSum[2] = {};
    const int qi_l = 16 * w + l;

    // per-thread V base: row (16tn+l) of V^T [d][t], col chunk quad*8
    const uint16_t* vbase = &Vtbf[(size_t)l * NROW + b * SEQ + 8 * quad];

    // ---- one k-tile step; DO1/M0/M1 compile-time at each call site ----
    auto body = [&](int kb, bool DO1, bool M0, bool M1) __attribute__((always_inline)) {
        const int cur = kb & 1, nxt = cur ^ 1;

        // ---- V fragments for CURRENT tile, direct from global (L2-hot).
        //      Issued first; consumed after QK+softmax (~500 cy cover). ----
        bf16x8 vb[4][2];
#pragma unroll
        for (int tn = 0; tn < 4; ++tn)
#pragma unroll
            for (int kh = 0; kh < 2; ++kh)
                vb[tn][kh] = *(const bf16x8*)(vbase + (size_t)(16 * tn) * NROW
                                              + kb * 64 + 32 * kh);

        // ---- K fragments from LDS (pi-row order) ----
        bf16x8 ka[4][2];
#pragma unroll
        for (int ts = 0; ts < 4; ++ts) {
            ka[ts][0] = *(const bf16x8*)&Ks[cur][16 * ts + l][quad * 8];
            ka[ts][1] = *(const bf16x8*)&Ks[cur][16 * ts + l][32 + quad * 8];
        }

        // ---- stage K tile kb+1 into idle buffer; issue loads for kb+2 ----
        if (kb < qt0) {
            *(uint4*)&Ks[nxt][sr][sc]     = kg0;
            *(uint4*)&Ks[nxt][sr][sc + 8] = kg1;
            if (kb + 1 < qt0) {
                const uint4* ks = (const uint4*)
                    &Kbf[(size_t)(b * SEQ + (kb + 2) * 64 + prow) * HD + sc];
                kg0 = ks[0]; kg1 = ks[1];
            }
        }

        // ---- QK^T for both tiles ----
        f32x4 accS0[4] = {}, accS1[4] = {};
#pragma unroll
        for (int ts = 0; ts < 4; ++ts) {
            accS0[ts] = __builtin_amdgcn_mfma_f32_16x16x32_bf16(ka[ts][0], qf[0][0], accS0[ts], 0, 0, 0);
            accS0[ts] = __builtin_amdgcn_mfma_f32_16x16x32_bf16(ka[ts][1], qf[0][1], accS0[ts], 0, 0, 0);
        }
        if (DO1) {
#pragma unroll
            for (int ts = 0; ts < 4; ++ts) {
                accS1[ts] = __builtin_amdgcn_mfma_f32_16x16x32_bf16(ka[ts][0], qf[1][0], accS1[ts], 0, 0, 0);
                accS1[ts] = __builtin_amdgcn_mfma_f32_16x16x32_bf16(ka[ts][1], qf[1][1], accS1[ts], 0, 0, 0);
            }
        }

        // ---- tile 0: exp2 / mask / in-register pa build / PV ----
        {
            float pv[16];
#pragma unroll
            for (int ts = 0; ts < 4; ++ts)
#pragma unroll
                for (int r = 0; r < 4; ++r)
                    pv[4 * ts + r] = exp2f(accS0[ts][r]);
            if (M0) {
                // k-position of pv[4ts+r] is 32(ts>=2) + 8quad + 4(ts&1) + r
#pragma unroll
                for (int ts = 0; ts < 4; ++ts)
#pragma unroll
                    for (int r = 0; r < 4; ++r)
                        if ((((ts & 2) << 4) + ((ts & 1) << 2) + 8 * quad + r) > qi_l)
                            pv[4 * ts + r] = 0.f;
            }
            union { uint32_t u[4]; bf16x8 v; } A0, A1;
#pragma unroll
            for (int j = 0; j < 4; ++j) A0.u[j] = cvtpk(pv[2 * j],     pv[2 * j + 1]);
#pragma unroll
            for (int j = 0; j < 4; ++j) A1.u[j] = cvtpk(pv[8 + 2 * j], pv[9 + 2 * j]);
#pragma unroll
            for (int tn = 0; tn < 4; ++tn) {
                accO[0][tn] = __builtin_amdgcn_mfma_f32_16x16x32_bf16(A0.v, vb[tn][0], accO[0][tn], 0, 0, 0);
                accO[0][tn] = __builtin_amdgcn_mfma_f32_16x16x32_bf16(A1.v, vb[tn][1], accO[0][tn], 0, 0, 0);
            }
            accSum[0] = __builtin_amdgcn_mfma_f32_16x16x32_bf16(A0.v, ones, accSum[0], 0, 0, 0);
            accSum[0] = __builtin_amdgcn_mfma_f32_16x16x32_bf16(A1.v, ones, accSum[0], 0, 0, 0);
        }
        // ---- tile 1 ----
        if (DO1) {
            float pv[16];
#pragma unroll
            for (int ts = 0; ts < 4; ++ts)
#pragma unroll
                for (int r = 0; r < 4; ++r)
                    pv[4 * ts + r] = exp2f(accS1[ts][r]);
            if (M1) {
#pragma unroll
                for (int ts = 0; ts < 4; ++ts)
#pragma unroll
                    for (int r = 0; r < 4; ++r)
                        if ((((ts & 2) << 4) + ((ts & 1) << 2) + 8 * quad + r) > qi_l)
                            pv[4 * ts + r] = 0.f;
            }
            union { uint32_t u[4]; bf16x8 v; } A0, A1;
#pragma unroll
            for (int j = 0; j < 4; ++j) A0.u[j] = cvtpk(pv[2 * j],     pv[2 * j + 1]);
#pragma unroll
            for (int j = 0; j < 4; ++j) A1.u[j] = cvtpk(pv[8 + 2 * j], pv[9 + 2 * j]);
#pragma unroll
            for (int tn = 0; tn < 4; ++tn) {
                accO[1][tn] = __builtin_amdgcn_mfma_f32_16x16x32_bf16(A0.v, vb[tn][0], accO[1][tn], 0, 0, 0);
                accO[1][tn] = __builtin_amdgcn_mfma_f32_16x16x32_bf16(A1.v, vb[tn][1], accO[1][tn], 0, 0, 0);
            }
            accSum[1] = __builtin_amdgcn_mfma_f32_16x16x32_bf16(A0.v, ones, accSum[1], 0, 0, 0);
            accSum[1] = __builtin_amdgcn_mfma_f32_16x16x32_bf16(A1.v, ones, accSum[1], 0, 0, 0);
        }

        if (kb < qt0) __syncthreads();   // Ks[cur] reads done before overwrite
    };

    // ---- segmented k-loop: branch-free bodies, peeled diagonals ----
    for (int kb = 0; kb < qt1; ++kb) body(kb, true,  false, false);
    body(qt1, true,  false, true);                 // tile-1 diagonal
    for (int kb = qt1 + 1; kb < qt0; ++kb) body(kb, false, false, false);
    body(qt0, false, true,  false);                // tile-0 diagonal

    // ---- epilogue: denominator lane-aligned with accO rows ----
#pragma unroll
    for (int t = 0; t < 2; ++t) {
        const int q0t = t ? q01 : q00;
#pragma unroll
        for (int r = 0; r < 4; ++r) {
            float invr = 1.0f / accSum[t][r];
            const int row = q0t + 16 * w + 4 * quad + r;
#pragma unroll
            for (int tn = 0; tn < 4; ++tn)
                Out[(size_t)(b * SEQ + row) * EMB + h * HD + 16 * tn + l] =
                    accO[t][tn][r] * invr;
        }
    }
}

// =====================================================================
// Fallback (proven): fp32 vector GEMM (writes same layouts).
// =====================================================================
__global__ __launch_bounds__(256) void qkv_gemm_vec(
    const float* __restrict__ X,  const float* __restrict__ Wq,
    const float* __restrict__ Wk, const float* __restrict__ Wv,
    float* __restrict__ Qout, uint16_t* __restrict__ Kbf,
    uint16_t* __restrict__ Vtbf)
{
    const int tid = threadIdx.x;
    const int tx = tid & 15, ty = tid >> 4;
    const int bx = blockIdx.x;
    const int m0 = blockIdx.y * 64;

    const float* W; int ldw, n0;
    if (bx < 16)       { W = Wq; ldw = EMB; n0 = bx * 64; }
    else if (bx == 16) { W = Wk; ldw = HD;  n0 = 0; }
    else               { W = Wv; ldw = HD;  n0 = 0; }

    __shared__ float sA[64][17];
    __shared__ float sB[16][64];

    float acc[4][4] = {};
    const int arow = tid >> 2, acol = (tid & 3) * 4;
    const int brow = tid >> 4, bcol = (tid & 15) * 4;

    for (int k0 = 0; k0 < EMB; k0 += 16) {
        float4 fa = *(const float4*)&X[(size_t)(m0 + arow) * EMB + k0 + acol];
        float4 fb = *(const float4*)&W[(size_t)(k0 + brow) * ldw + n0 + bcol];
        sA[arow][acol + 0] = fa.x; sA[arow][acol + 1] = fa.y;
        sA[arow][acol + 2] = fa.z; sA[arow][acol + 3] = fa.w;
        sB[brow][bcol + 0] = fb.x; sB[brow][bcol + 1] = fb.y;
        sB[brow][bcol + 2] = fb.z; sB[brow][bcol + 3] = fb.w;
        __syncthreads();
#pragma unroll
        for (int kk = 0; kk < 16; ++kk) {
            float a0 = sA[4 * ty + 0][kk];
            float a1 = sA[4 * ty + 1][kk];
            float a2 = sA[4 * ty + 2][kk];
            float a3 = sA[4 * ty + 3][kk];
            float4 bq = *(const float4*)&sB[kk][4 * tx];
            acc[0][0] += a0 * bq.x; acc[0][1] += a0 * bq.y; acc[0][2] += a0 * bq.z; acc[0][3] += a0 * bq.w;
            acc[1][0] += a1 * bq.x; acc[1][1] += a1 * bq.y; acc[1][2] += a1 * bq.z; acc[1][3] += a1 * bq.w;
            acc[2][0] += a2 * bq.x; acc[2][1] += a2 * bq.y; acc[2][2] += a2 * bq.z; acc[2][3] += a2 * bq.w;
            acc[3][0] += a3 * bq.x; acc[3][1] += a3 * bq.y; acc[3][2] += a3 * bq.z; acc[3][3] += a3 * bq.w;
        }
        __syncthreads();
    }

    if (bx < 16) {
#pragma unroll
        for (int i = 0; i < 4; ++i)
            *(float4*)&Qout[(size_t)(m0 + 4 * ty + i) * EMB + n0 + 4 * tx] =
                make_float4(acc[i][0], acc[i][1], acc[i][2], acc[i][3]);
    } else if (bx == 16) {
#pragma unroll
        for (int i = 0; i < 4; ++i) {
            ushort4 u; u.x = f2bf(acc[i][0]); u.y = f2bf(acc[i][1]);
            u.z = f2bf(acc[i][2]); u.w = f2bf(acc[i][3]);
            *(ushort4*)&Kbf[(size_t)(m0 + 4 * ty + i) * HD + 4 * tx] = u;
        }
    } else {
#pragma unroll
        for (int j = 0; j < 4; ++j) {
            ushort4 u; u.x = f2bf(acc[0][j]); u.y = f2bf(acc[1][j]);
            u.z = f2bf(acc[2][j]); u.w = f2bf(acc[3][j]);
            *(ushort4*)&Vtbf[(size_t)(4 * tx + j) * NROW + m0 + 4 * ty] = u;
        }
    }
}

extern "C" void kernel_launch(void* const* d_in, const int* in_sizes, int n_in,
                              void* d_out, int out_size, void* d_ws, size_t ws_size,
                              hipStream_t stream) {
    const float* X  = (const float*)d_in[0];
    const float* Wq = (const float*)d_in[1];
    const float* Wk = (const float*)d_in[2];
    const float* Wv = (const float*)d_in[3];
    float* OutP = (float*)d_out;

    // ws layout (11.5 MiB; >=12 MiB proven available on this harness):
    //   Xbf  [4096][1024] bf16   8 MiB  @ 0
    //   Wqt  [1024][1024] bf16   2 MiB  @ 8 MiB
    //   Wkt  [64][1024]   bf16 128 KiB  @ 10 MiB
    //   Wvt  [64][1024]   bf16 128 KiB  @ 10.25 MiB
    //   Kbf  [4096][64]   bf16 512 KiB  @ 10.5 MiB
    //   Vtbf [64][4096]   bf16 512 KiB  @ 11 MiB
    char* ws = (char*)d_ws;
    const size_t MB = 1024 * 1024;
    uint16_t* Xbf  = (uint16_t*)(ws);
    uint16_t* Wqt  = (uint16_t*)(ws + 8 * MB);
    uint16_t* Wkt  = (uint16_t*)(ws + 10 * MB);
    uint16_t* Wvt  = (uint16_t*)(ws + 10 * MB + 256 * 1024);
    uint16_t* Kbf  = (uint16_t*)(ws + 10 * MB + 512 * 1024);
    uint16_t* Vtbf = (uint16_t*)(ws + 11 * MB);

    if (ws_size >= 12 * MB) {
        prep<<<2336, 256, 0, stream>>>(X, Xbf, Wq, Wk, Wv, Wqt, Wkt, Wvt);
        qkv_gemm_mfma5<<<dim3(9, 64), 256, 0, stream>>>(Xbf, Wqt, Wkt, Wvt,
                                                        OutP, Kbf, Vtbf);
        mqa_attn<<<dim3(16, NH, BSZ), 256, 0, stream>>>(Kbf, Vtbf, OutP);
    } else {
        uint16_t* KbfS  = (uint16_t*)d_ws;
        uint16_t* VtbfS = KbfS + (size_t)NROW * HD;
        qkv_gemm_vec<<<dim3(18, 64), 256, 0, stream>>>(X, Wq, Wk, Wv, OutP, KbfS, VtbfS);
        mqa_attn<<<dim3(16, NH, BSZ), 256, 0, stream>>>(KbfS, VtbfS, OutP);
    }
}

// Round 5
// 135.029 us; speedup vs baseline: 1.2060x; 1.2060x over previous
//
#include <hip/hip_runtime.h>
#include <stdint.h>

#define NH   16
#define EMB  1024
#define HD   64
#define BSZ  2
#define SEQ  2048
#define NROW (BSZ * SEQ)          // 4096

typedef __attribute__((ext_vector_type(8))) short bf16x8;   // 8 bf16 = 4 VGPRs
typedef __attribute__((ext_vector_type(4))) float f32x4;    // MFMA C/D

__device__ __forceinline__ uint16_t f2bf(float f) {
    union { float f; uint32_t i; } v; v.f = f;
    uint32_t r = v.i + 0x7FFFu + ((v.i >> 16) & 1u);  // RNE
    return (uint16_t)(r >> 16);
}
__device__ __forceinline__ uint32_t pack2(float a, float b) {
    return (uint32_t)f2bf(a) | ((uint32_t)f2bf(b) << 16);
}
// single-instruction packed f32->bf16 (lo=a, hi=b)
__device__ __forceinline__ uint32_t cvtpk(float a, float b) {
    uint32_t r;
    asm("v_cvt_pk_bf16_f32 %0, %1, %2" : "=v"(r) : "v"(a), "v"(b));
    return r;
}

// async global->LDS, 16 B per lane, wave-uniform LDS base
__device__ __forceinline__ void gl2lds16(const uint16_t* g, uint16_t* l) {
    __builtin_amdgcn_global_load_lds(
        static_cast<const uint32_t*>(static_cast<const void*>(g)),
        static_cast<uint32_t*>(static_cast<void*>(l)), 16, 0, 0);
}

// =====================================================================
// Prep (fused): blocks 0..2047 convert X fp32->bf16;
// blocks 2048..2335 transpose W fp32 [k][n] -> bf16 Wt[n][k].
// =====================================================================
__global__ __launch_bounds__(256) void prep(
    const float* __restrict__ X, uint16_t* __restrict__ Xbf,
    const float* __restrict__ Wq, const float* __restrict__ Wk,
    const float* __restrict__ Wv, uint16_t* __restrict__ Wqt,
    uint16_t* __restrict__ Wkt, uint16_t* __restrict__ Wvt)
{
    __shared__ uint16_t T[64][72];
    const int tid = threadIdx.x;
    if (blockIdx.x < 2048) {
        size_t idx = ((size_t)blockIdx.x * 256 + tid) * 8;
        float4 a = *(const float4*)&X[idx];
        float4 b = *(const float4*)&X[idx + 4];
        *(uint4*)&Xbf[idx] = make_uint4(pack2(a.x, a.y), pack2(a.z, a.w),
                                        pack2(b.x, b.y), pack2(b.z, b.w));
        return;
    }
    const int id = blockIdx.x - 2048;
    const float* W; uint16_t* Wt; int k0, n0, ldw;
    if (id < 256)      { W = Wq; Wt = Wqt; k0 = (id >> 4) * 64; n0 = (id & 15) * 64; ldw = EMB; }
    else if (id < 272) { W = Wk; Wt = Wkt; k0 = (id - 256) * 64; n0 = 0; ldw = HD; }
    else               { W = Wv; Wt = Wvt; k0 = (id - 272) * 64; n0 = 0; ldw = HD; }

    const int r = tid >> 2, c4 = (tid & 3) * 16;
#pragma unroll
    for (int i = 0; i < 4; ++i) {
        float4 wv = *(const float4*)&W[(size_t)(k0 + r) * ldw + n0 + c4 + 4 * i];
        T[r][c4 + 4 * i + 0] = f2bf(wv.x); T[r][c4 + 4 * i + 1] = f2bf(wv.y);
        T[r][c4 + 4 * i + 2] = f2bf(wv.z); T[r][c4 + 4 * i + 3] = f2bf(wv.w);
    }
    __syncthreads();
    const int n = tid >> 2, kk = (tid & 3) * 16;
    uint32_t o[8];
#pragma unroll
    for (int i = 0; i < 8; ++i)
        o[i] = (uint32_t)T[kk + 2 * i][n] | ((uint32_t)T[kk + 2 * i + 1][n] << 16);
    uint16_t* dst = &Wt[(size_t)(n0 + n) * EMB + k0 + kk];
    *(uint4*)dst       = make_uint4(o[0], o[1], o[2], o[3]);
    *(uint4*)(dst + 8) = make_uint4(o[4], o[5], o[6], o[7]);
}

// =====================================================================
// Kernel 1: MFMA projection GEMM v5.  64M x 128N tiles, BK=64,
// grid (9, 64) = 576 blocks.  (unchanged this round)
// =====================================================================
__global__ __launch_bounds__(256) void qkv_gemm_mfma5(
    const uint16_t* __restrict__ Xbf, const uint16_t* __restrict__ Wqt,
    const uint16_t* __restrict__ Wkt, const uint16_t* __restrict__ Wvt,
    float* __restrict__ Qout, uint16_t* __restrict__ Kbf,
    uint16_t* __restrict__ Vtbf)
{
    const int tid  = threadIdx.x;
    const int w    = tid >> 6, lane = tid & 63;
    const int l    = lane & 15, quad = lane >> 4;
    const int wm   = w & 1, wn = w >> 1;      // wave: 32m x 64n quadrant
    const int nt   = blockIdx.x;
    const int m0   = blockIdx.y * 64;

    __shared__ uint16_t As[2][64 * 64];    // 8 KB per buffer
    __shared__ uint16_t Bs[2][128 * 64];   // 16 KB per buffer

    // ---- staging: per-lane global source for swizzled LDS granules ----
    const uint16_t* gA[2]; uint32_t ldsA[2];
    const uint16_t* gB[4]; uint32_t ldsB[4];
#pragma unroll
    for (int i = 0; i < 2; ++i) {
        int G = (w * 2 + i) * 64 + lane;
        int r = G >> 3, cg = (G & 7) ^ (r & 7);
        gA[i] = &Xbf[(size_t)(m0 + r) * EMB + cg * 8];
        ldsA[i] = (w * 2 + i) * 512;              // elems, wave-uniform
    }
#pragma unroll
    for (int i = 0; i < 4; ++i) {
        int G = (w * 4 + i) * 64 + lane;
        int r = G >> 3, cg = (G & 7) ^ (r & 7);
        const uint16_t* bs;
        if (nt < 8)      bs = &Wqt[(size_t)(nt * 128 + r) * EMB + cg * 8];
        else if (r < 64) bs = &Wkt[(size_t)r * EMB + cg * 8];
        else             bs = &Wvt[(size_t)(r - 64) * EMB + cg * 8];
        gB[i] = bs;
        ldsB[i] = (w * 4 + i) * 512;
    }

    // ---- fragment read offsets (elems), loop-invariant ----
    uint32_t offA[2][2], offB[4][2];
#pragma unroll
    for (int i = 0; i < 2; ++i)
#pragma unroll
        for (int kh = 0; kh < 2; ++kh) {
            int row = 32 * wm + 16 * i + l;
            offA[i][kh] = row * 64 + (((kh * 4 + quad) ^ (row & 7)) * 8);
        }
#pragma unroll
    for (int j = 0; j < 4; ++j)
#pragma unroll
        for (int kh = 0; kh < 2; ++kh) {
            int row = 64 * wn + 16 * j + l;
            offB[j][kh] = row * 64 + (((kh * 4 + quad) ^ (row & 7)) * 8);
        }

    f32x4 acc[2][4] = {};

#pragma unroll
    for (int i = 0; i < 2; ++i) { gl2lds16(gA[i], &As[0][ldsA[i]]); gA[i] += 64; }
#pragma unroll
    for (int i = 0; i < 4; ++i) { gl2lds16(gB[i], &Bs[0][ldsB[i]]); gB[i] += 64; }
    __syncthreads();

    for (int ks = 0; ks < 16; ++ks) {
        const int cur = ks & 1, nxt = cur ^ 1;
        if (ks < 15) {
#pragma unroll
            for (int i = 0; i < 2; ++i) { gl2lds16(gA[i], &As[nxt][ldsA[i]]); gA[i] += 64; }
#pragma unroll
            for (int i = 0; i < 4; ++i) { gl2lds16(gB[i], &Bs[nxt][ldsB[i]]); gB[i] += 64; }
        }
#pragma unroll
        for (int kh = 0; kh < 2; ++kh) {
            bf16x8 af[2], bfr[4];
#pragma unroll
            for (int i = 0; i < 2; ++i) af[i] = *(const bf16x8*)&As[cur][offA[i][kh]];
#pragma unroll
            for (int j = 0; j < 4; ++j) bfr[j] = *(const bf16x8*)&Bs[cur][offB[j][kh]];
#pragma unroll
            for (int i = 0; i < 2; ++i)
#pragma unroll
                for (int j = 0; j < 4; ++j)
                    acc[i][j] = __builtin_amdgcn_mfma_f32_16x16x32_bf16(
                        af[i], bfr[j], acc[i][j], 0, 0, 0);
        }
        __syncthreads();
    }

    // ---- epilogue.  C layout: col = l (n), row = quad*4 + r (m). ----
    if (nt < 8) {             // Q -> fp32 d_out
#pragma unroll
        for (int i = 0; i < 2; ++i)
#pragma unroll
            for (int j = 0; j < 4; ++j)
#pragma unroll
                for (int r = 0; r < 4; ++r)
                    Qout[(size_t)(m0 + 32 * wm + 16 * i + 4 * quad + r) * EMB
                         + nt * 128 + 64 * wn + 16 * j + l] = acc[i][j][r];
    } else if (wn == 0) {     // K -> bf16 [t][d]
#pragma unroll
        for (int i = 0; i < 2; ++i)
#pragma unroll
            for (int j = 0; j < 4; ++j)
#pragma unroll
                for (int r = 0; r < 4; ++r)
                    Kbf[(size_t)(m0 + 32 * wm + 16 * i + 4 * quad + r) * HD
                        + 16 * j + l] = f2bf(acc[i][j][r]);
    } else {                  // V -> bf16 transposed [d][t]
#pragma unroll
        for (int i = 0; i < 2; ++i)
#pragma unroll
            for (int j = 0; j < 4; ++j)
#pragma unroll
                for (int r = 0; r < 4; ++r)
                    Vtbf[(size_t)(16 * j + l) * NROW
                         + m0 + 32 * wm + 16 * i + 4 * quad + r] = f2bf(acc[i][j][r]);
    }
}

// =====================================================================
// Kernel 2: causal MQA flash attention, COMPLEMENTARY-PAIR blocks.
// R16 = R4's pi-K + in-register P (HW-verified) with V restored to
// double-buffered LDS (R4's direct-global V was TA-serialized: 16
// cache lines per load -> all pipes idle, 70us).  In-loop LDS per
// wave-body: 16 b128 reads + 4 b128 staging writes (R2 had 20 reads +
// 12 writes + P round-trip).
// Grid (16, NH, BSZ) = 512 blocks (grid-limited: 2 blocks/CU).
// =====================================================================
__global__ __launch_bounds__(256) void mqa_attn(
    const uint16_t* __restrict__ Kbf, const uint16_t* __restrict__ Vtbf,
    float* __restrict__ Out)
{
    const int tid  = threadIdx.x;
    const int w    = tid >> 6;
    const int lane = tid & 63;
    const int l    = lane & 15;
    const int quad = lane >> 4;
    const int i  = blockIdx.x;            // 0..15 (i=0 longest)
    const int h  = blockIdx.y, b = blockIdx.z;
    const int qt0 = 31 - i, qt1 = i;      // big, small q-tile
    const int q00 = qt0 * 64, q01 = qt1 * 64;

    __shared__ __align__(16) uint16_t Ks[2][64][72];   // K tiles (dbuf), pi-rows
    __shared__ __align__(16) uint16_t Vs[2][64][72];   // V^T tiles (dbuf)
    __shared__ __align__(16) uint16_t Ps[2][64][72];   // Q staging

    const float C = 0.125f * 1.4426950408889634f;      // scale * log2e
    const int sr = tid >> 2, sc = (tid & 3) * 16;
    // LDS row sr holds global k-row pi(sr)=32*b5 + 8*(b3b2) + 4*b4 + b1b0
    const int prow = (sr & 32) + ((sr >> 2) & 3) * 8 + ((sr & 16) >> 2) + (sr & 3);

    // ---- stage Q for both q-tiles (pre-scaled) into Ps (wave-local rows) ----
#pragma unroll
    for (int t = 0; t < 2; ++t) {
        const int q0t = t ? q01 : q00;
        const float* src = &Out[(size_t)(b * SEQ + q0t + sr) * EMB + h * HD + sc];
        float4 f0 = *(const float4*)(src + 0);
        float4 f1 = *(const float4*)(src + 4);
        float4 f2 = *(const float4*)(src + 8);
        float4 f3 = *(const float4*)(src + 12);
        *(uint4*)&Ps[t][sr][sc] =
            make_uint4(pack2(f0.x * C, f0.y * C), pack2(f0.z * C, f0.w * C),
                       pack2(f1.x * C, f1.y * C), pack2(f1.z * C, f1.w * C));
        *(uint4*)&Ps[t][sr][sc + 8] =
            make_uint4(pack2(f2.x * C, f2.y * C), pack2(f2.z * C, f2.w * C),
                       pack2(f3.x * C, f3.y * C), pack2(f3.z * C, f3.w * C));
    }

    // ---- K (pi rows) + V tile 0 -> LDS; tile 1 -> regs ----
    uint4 kg0, kg1, vg0, vg1;
    {
        const uint4* ks = (const uint4*)&Kbf[(size_t)(b * SEQ + prow) * HD + sc];
        kg0 = ks[0]; kg1 = ks[1];
        const uint4* vs = (const uint4*)&Vtbf[(size_t)sr * NROW + b * SEQ + sc];
        vg0 = vs[0]; vg1 = vs[1];
    }
    *(uint4*)&Ks[0][sr][sc]     = kg0;
    *(uint4*)&Ks[0][sr][sc + 8] = kg1;
    *(uint4*)&Vs[0][sr][sc]     = vg0;
    *(uint4*)&Vs[0][sr][sc + 8] = vg1;
    {   // qt0 >= 16 always, tile 1 exists
        const uint4* ks = (const uint4*)&Kbf[(size_t)(b * SEQ + 64 + prow) * HD + sc];
        kg0 = ks[0]; kg1 = ks[1];
        const uint4* vs = (const uint4*)&Vtbf[(size_t)sr * NROW + b * SEQ + 64 + sc];
        vg0 = vs[0]; vg1 = vs[1];
    }
    __syncthreads();

    // ---- Q B-fragments for both q-tiles ----
    bf16x8 qf[2][2];
#pragma unroll
    for (int t = 0; t < 2; ++t) {
        qf[t][0] = *(const bf16x8*)&Ps[t][16 * w + l][quad * 8];
        qf[t][1] = *(const bf16x8*)&Ps[t][16 * w + l][32 + quad * 8];
    }

    bf16x8 ones;
#pragma unroll
    for (int j = 0; j < 8; ++j) ones[j] = (short)0x3F80;   // bf16 1.0

    f32x4 accO[2][4] = {};
    f32x4 accSum[2] = {};
    const int qi_l = 16 * w + l;

    // ---- one k-tile step; DO1/M0/M1 compile-time at each call site ----
    auto body = [&](int kb, bool DO1, bool M0, bool M1) __attribute__((always_inline)) {
        const int cur = kb & 1, nxt = cur ^ 1;

        // ---- K fragments from LDS (pi-row order) ----
        bf16x8 ka[4][2];
#pragma unroll
        for (int ts = 0; ts < 4; ++ts) {
            ka[ts][0] = *(const bf16x8*)&Ks[cur][16 * ts + l][quad * 8];
            ka[ts][1] = *(const bf16x8*)&Ks[cur][16 * ts + l][32 + quad * 8];
        }
        // ---- V fragments from LDS (B k-index = 8quad+j, +32 for kh=1) ----
        bf16x8 vb[4][2];
#pragma unroll
        for (int tn = 0; tn < 4; ++tn) {
            vb[tn][0] = *(const bf16x8*)&Vs[cur][16 * tn + l][quad * 8];
            vb[tn][1] = *(const bf16x8*)&Vs[cur][16 * tn + l][32 + quad * 8];
        }

        // ---- stage tile kb+1 into idle buffers; issue loads for kb+2 ----
        if (kb < qt0) {
            *(uint4*)&Ks[nxt][sr][sc]     = kg0;
            *(uint4*)&Ks[nxt][sr][sc + 8] = kg1;
            *(uint4*)&Vs[nxt][sr][sc]     = vg0;
            *(uint4*)&Vs[nxt][sr][sc + 8] = vg1;
            if (kb + 1 < qt0) {
                const int k0n = (kb + 2) * 64;
                const uint4* ks = (const uint4*)
                    &Kbf[(size_t)(b * SEQ + k0n + prow) * HD + sc];
                kg0 = ks[0]; kg1 = ks[1];
                const uint4* vs = (const uint4*)
                    &Vtbf[(size_t)sr * NROW + b * SEQ + k0n + sc];
                vg0 = vs[0]; vg1 = vs[1];
            }
        }

        // ---- QK^T for both tiles ----
        f32x4 accS0[4] = {}, accS1[4] = {};
#pragma unroll
        for (int ts = 0; ts < 4; ++ts) {
            accS0[ts] = __builtin_amdgcn_mfma_f32_16x16x32_bf16(ka[ts][0], qf[0][0], accS0[ts], 0, 0, 0);
            accS0[ts] = __builtin_amdgcn_mfma_f32_16x16x32_bf16(ka[ts][1], qf[0][1], accS0[ts], 0, 0, 0);
        }
        if (DO1) {
#pragma unroll
            for (int ts = 0; ts < 4; ++ts) {
                accS1[ts] = __builtin_amdgcn_mfma_f32_16x16x32_bf16(ka[ts][0], qf[1][0], accS1[ts], 0, 0, 0);
                accS1[ts] = __builtin_amdgcn_mfma_f32_16x16x32_bf16(ka[ts][1], qf[1][1], accS1[ts], 0, 0, 0);
            }
        }

        // ---- tile 0: exp2 / mask / in-register pa build / PV ----
        {
            float pv[16];
#pragma unroll
            for (int ts = 0; ts < 4; ++ts)
#pragma unroll
                for (int r = 0; r < 4; ++r)
                    pv[4 * ts + r] = exp2f(accS0[ts][r]);
            if (M0) {
                // k-position of pv[4ts+r] is 32(ts>=2) + 8quad + 4(ts&1) + r
#pragma unroll
                for (int ts = 0; ts < 4; ++ts)
#pragma unroll
                    for (int r = 0; r < 4; ++r)
                        if ((((ts & 2) << 4) + ((ts & 1) << 2) + 8 * quad + r) > qi_l)
                            pv[4 * ts + r] = 0.f;
            }
            union { uint32_t u[4]; bf16x8 v; } A0, A1;
#pragma unroll
            for (int j = 0; j < 4; ++j) A0.u[j] = cvtpk(pv[2 * j],     pv[2 * j + 1]);
#pragma unroll
            for (int j = 0; j < 4; ++j) A1.u[j] = cvtpk(pv[8 + 2 * j], pv[9 + 2 * j]);
#pragma unroll
            for (int tn = 0; tn < 4; ++tn) {
                accO[0][tn] = __builtin_amdgcn_mfma_f32_16x16x32_bf16(A0.v, vb[tn][0], accO[0][tn], 0, 0, 0);
                accO[0][tn] = __builtin_amdgcn_mfma_f32_16x16x32_bf16(A1.v, vb[tn][1], accO[0][tn], 0, 0, 0);
            }
            accSum[0] = __builtin_amdgcn_mfma_f32_16x16x32_bf16(A0.v, ones, accSum[0], 0, 0, 0);
            accSum[0] = __builtin_amdgcn_mfma_f32_16x16x32_bf16(A1.v, ones, accSum[0], 0, 0, 0);
        }
        // ---- tile 1 ----
        if (DO1) {
            float pv[16];
#pragma unroll
            for (int ts = 0; ts < 4; ++ts)
#pragma unroll
                for (int r = 0; r < 4; ++r)
                    pv[4 * ts + r] = exp2f(accS1[ts][r]);
            if (M1) {
#pragma unroll
                for (int ts = 0; ts < 4; ++ts)
#pragma unroll
                    for (int r = 0; r < 4; ++r)
                        if ((((ts & 2) << 4) + ((ts & 1) << 2) + 8 * quad + r) > qi_l)
                            pv[4 * ts + r] = 0.f;
            }
            union { uint32_t u[4]; bf16x8 v; } A0, A1;
#pragma unroll
            for (int j = 0; j < 4; ++j) A0.u[j] = cvtpk(pv[2 * j],     pv[2 * j + 1]);
#pragma unroll
            for (int j = 0; j < 4; ++j) A1.u[j] = cvtpk(pv[8 + 2 * j], pv[9 + 2 * j]);
#pragma unroll
            for (int tn = 0; tn < 4; ++tn) {
                accO[1][tn] = __builtin_amdgcn_mfma_f32_16x16x32_bf16(A0.v, vb[tn][0], accO[1][tn], 0, 0, 0);
                accO[1][tn] = __builtin_amdgcn_mfma_f32_16x16x32_bf16(A1.v, vb[tn][1], accO[1][tn], 0, 0, 0);
            }
            accSum[1] = __builtin_amdgcn_mfma_f32_16x16x32_bf16(A0.v, ones, accSum[1], 0, 0, 0);
            accSum[1] = __builtin_amdgcn_mfma_f32_16x16x32_bf16(A1.v, ones, accSum[1], 0, 0, 0);
        }

        if (kb < qt0) __syncthreads();   // [cur] reads done before overwrite
    };

    // ---- segmented k-loop: branch-free bodies, peeled diagonals ----
    for (int kb = 0; kb < qt1; ++kb) body(kb, true,  false, false);
    body(qt1, true,  false, true);                 // tile-1 diagonal
    for (int kb = qt1 + 1; kb < qt0; ++kb) body(kb, false, false, false);
    body(qt0, false, true,  false);                // tile-0 diagonal

    // ---- epilogue: denominator lane-aligned with accO rows ----
#pragma unroll
    for (int t = 0; t < 2; ++t) {
        const int q0t = t ? q01 : q00;
#pragma unroll
        for (int r = 0; r < 4; ++r) {
            float invr = 1.0f / accSum[t][r];
            const int row = q0t + 16 * w + 4 * quad + r;
#pragma unroll
            for (int tn = 0; tn < 4; ++tn)
                Out[(size_t)(b * SEQ + row) * EMB + h * HD + 16 * tn + l] =
                    accO[t][tn][r] * invr;
        }
    }
}

// =====================================================================
// Fallback (proven): fp32 vector GEMM (writes same layouts).
// =====================================================================
__global__ __launch_bounds__(256) void qkv_gemm_vec(
    const float* __restrict__ X,  const float* __restrict__ Wq,
    const float* __restrict__ Wk, const float* __restrict__ Wv,
    float* __restrict__ Qout, uint16_t* __restrict__ Kbf,
    uint16_t* __restrict__ Vtbf)
{
    const int tid = threadIdx.x;
    const int tx = tid & 15, ty = tid >> 4;
    const int bx = blockIdx.x;
    const int m0 = blockIdx.y * 64;

    const float* W; int ldw, n0;
    if (bx < 16)       { W = Wq; ldw = EMB; n0 = bx * 64; }
    else if (bx == 16) { W = Wk; ldw = HD;  n0 = 0; }
    else               { W = Wv; ldw = HD;  n0 = 0; }

    __shared__ float sA[64][17];
    __shared__ float sB[16][64];

    float acc[4][4] = {};
    const int arow = tid >> 2, acol = (tid & 3) * 4;
    const int brow = tid >> 4, bcol = (tid & 15) * 4;

    for (int k0 = 0; k0 < EMB; k0 += 16) {
        float4 fa = *(const float4*)&X[(size_t)(m0 + arow) * EMB + k0 + acol];
        float4 fb = *(const float4*)&W[(size_t)(k0 + brow) * ldw + n0 + bcol];
        sA[arow][acol + 0] = fa.x; sA[arow][acol + 1] = fa.y;
        sA[arow][acol + 2] = fa.z; sA[arow][acol + 3] = fa.w;
        sB[brow][bcol + 0] = fb.x; sB[brow][bcol + 1] = fb.y;
        sB[brow][bcol + 2] = fb.z; sB[brow][bcol + 3] = fb.w;
        __syncthreads();
#pragma unroll
        for (int kk = 0; kk < 16; ++kk) {
            float a0 = sA[4 * ty + 0][kk];
            float a1 = sA[4 * ty + 1][kk];
            float a2 = sA[4 * ty + 2][kk];
            float a3 = sA[4 * ty + 3][kk];
            float4 bq = *(const float4*)&sB[kk][4 * tx];
            acc[0][0] += a0 * bq.x; acc[0][1] += a0 * bq.y; acc[0][2] += a0 * bq.z; acc[0][3] += a0 * bq.w;
            acc[1][0] += a1 * bq.x; acc[1][1] += a1 * bq.y; acc[1][2] += a1 * bq.z; acc[1][3] += a1 * bq.w;
            acc[2][0] += a2 * bq.x; acc[2][1] += a2 * bq.y; acc[2][2] += a2 * bq.z; acc[2][3] += a2 * bq.w;
            acc[3][0] += a3 * bq.x; acc[3][1] += a3 * bq.y; acc[3][2] += a3 * bq.z; acc[3][3] += a3 * bq.w;
        }
        __syncthreads();
    }

    if (bx < 16) {
#pragma unroll
        for (int i = 0; i < 4; ++i)
            *(float4*)&Qout[(size_t)(m0 + 4 * ty + i) * EMB + n0 + 4 * tx] =
                make_float4(acc[i][0], acc[i][1], acc[i][2], acc[i][3]);
    } else if (bx == 16) {
#pragma unroll
        for (int i = 0; i < 4; ++i) {
            ushort4 u; u.x = f2bf(acc[i][0]); u.y = f2bf(acc[i][1]);
            u.z = f2bf(acc[i][2]); u.w = f2bf(acc[i][3]);
            *(ushort4*)&Kbf[(size_t)(m0 + 4 * ty + i) * HD + 4 * tx] = u;
        }
    } else {
#pragma unroll
        for (int j = 0; j < 4; ++j) {
            ushort4 u; u.x = f2bf(acc[0][j]); u.y = f2bf(acc[1][j]);
            u.z = f2bf(acc[2][j]); u.w = f2bf(acc[3][j]);
            *(ushort4*)&Vtbf[(size_t)(4 * tx + j) * NROW + m0 + 4 * ty] = u;
        }
    }
}

extern "C" void kernel_launch(void* const* d_in, const int* in_sizes, int n_in,
                              void* d_out, int out_size, void* d_ws, size_t ws_size,
                              hipStream_t stream) {
    const float* X  = (const float*)d_in[0];
    const float* Wq = (const float*)d_in[1];
    const float* Wk = (const float*)d_in[2];
    const float* Wv = (const float*)d_in[3];
    float* OutP = (float*)d_out;

    // ws layout (11.5 MiB; >=12 MiB proven available on this harness):
    //   Xbf  [4096][1024] bf16   8 MiB  @ 0
    //   Wqt  [1024][1024] bf16   2 MiB  @ 8 MiB
    //   Wkt  [64][1024]   bf16 128 KiB  @ 10 MiB
    //   Wvt  [64][1024]   bf16 128 KiB  @ 10.25 MiB
    //   Kbf  [4096][64]   bf16 512 KiB  @ 10.5 MiB
    //   Vtbf [64][4096]   bf16 512 KiB  @ 11 MiB
    char* ws = (char*)d_ws;
    const size_t MB = 1024 * 1024;
    uint16_t* Xbf  = (uint16_t*)(ws);
    uint16_t* Wqt  = (uint16_t*)(ws + 8 * MB);
    uint16_t* Wkt  = (uint16_t*)(ws + 10 * MB);
    uint16_t* Wvt  = (uint16_t*)(ws + 10 * MB + 256 * 1024);
    uint16_t* Kbf  = (uint16_t*)(ws + 10 * MB + 512 * 1024);
    uint16_t* Vtbf = (uint16_t*)(ws + 11 * MB);

    if (ws_size >= 12 * MB) {
        prep<<<2336, 256, 0, stream>>>(X, Xbf, Wq, Wk, Wv, Wqt, Wkt, Wvt);
        qkv_gemm_mfma5<<<dim3(9, 64), 256, 0, stream>>>(Xbf, Wqt, Wkt, Wvt,
                                                        OutP, Kbf, Vtbf);
        mqa_attn<<<dim3(16, NH, BSZ), 256, 0, stream>>>(Kbf, Vtbf, OutP);
    } else {
        uint16_t* KbfS  = (uint16_t*)d_ws;
        uint16_t* VtbfS = KbfS + (size_t)NROW * HD;
        qkv_gemm_vec<<<dim3(18, 64), 256, 0, stream>>>(X, Wq, Wk, Wv, OutP, KbfS, VtbfS);
        mqa_attn<<<dim3(16, NH, BSZ), 256, 0, stream>>>(KbfS, VtbfS, OutP);
    }
}